// Round 2
// baseline (144.691 us; speedup 1.0000x reference)
//
#include <hip/hip_runtime.h>
#include <hip/hip_bf16.h>

// DecorrelationGradient, KAPPA = 0.5:
//   out = 0.5 * (X^T X / N) - 0.5   (diag terms cancel exactly at k=0.5)
// X [16384, 768] fp32.
//
// K1: transpose+cast X -> XT [768,16384] bf16 in d_ws (conflict-free LDS tile)
// K2: init d_out = -0.5
// K3: MFMA GEMM, symmetric: only upper tile-pairs (mi<=ni), 128x128 tile,
//     BK=32, KSPLIT=32, atomicAdd scaled partials onto d_out
// K4: mirror upper tiles -> lower tiles

#define D_DIM   768
#define K_DIM   16384
#define KSPLIT  32
#define KCHUNK  (K_DIM / KSPLIT)   // 512 -> 16 iters of BK=32

typedef __attribute__((ext_vector_type(8))) short short8;     // bf16 A/B frag (4 VGPRs)
typedef __attribute__((ext_vector_type(4))) float floatx4;    // fp32 C/D frag

typedef __attribute__((address_space(3))) unsigned short lds_ushort;
typedef __attribute__((address_space(1))) const unsigned short g_ushort;

__device__ __forceinline__ void load_lds16(const unsigned short* g, unsigned short* l) {
  __builtin_amdgcn_global_load_lds((g_ushort*)g, (lds_ushort*)l, 16, 0, 0);
}

__device__ __forceinline__ unsigned short f2bf(float f) {
  unsigned int u = __float_as_uint(f);
  u += 0x7fffu + ((u >> 16) & 1u);
  return (unsigned short)(u >> 16);
}

// ---------------- K1: transpose + cast -------------------------------------
// x [16384,768] f32 -> xt [768,16384] bf16. 64x64 tiles.
// LDS tile [n][d] with row stride 66 shorts = 33 dwords (odd) so that:
//   - phase-1 ushort2 writes: bank = (n + 2*c4 + q) % 32 -> <=2 lanes/bank (free)
//   - phase-2 u16 reads: bank = (8*ck + j + d/2) % 32 -> 2 lanes/dword broadcast (free)
__global__ __launch_bounds__(256) void transpose_cast_kernel(
    const float* __restrict__ x, unsigned short* __restrict__ xt) {
  __shared__ __align__(16) unsigned short tile[64 * 66];
  const int d0 = blockIdx.x * 64;    // 12 tiles over d
  const int n0 = blockIdx.y * 64;    // 256 tiles over n
  const int t  = threadIdx.x;
  const int c4 = t & 15;             // float4 index along d
  const int r  = t >> 4;             // n row group
#pragma unroll
  for (int i = 0; i < 4; ++i) {
    const int n = r + 16 * i;
    float4 v = *(const float4*)(x + (size_t)(n0 + n) * D_DIM + d0 + c4 * 4);
    ushort2 lo, hi;
    lo.x = f2bf(v.x); lo.y = f2bf(v.y);
    hi.x = f2bf(v.z); hi.y = f2bf(v.w);
    *(ushort2*)&tile[n * 66 + c4 * 4]     = lo;
    *(ushort2*)&tile[n * 66 + c4 * 4 + 2] = hi;
  }
  __syncthreads();
  const int ck = t & 7;              // 16B chunk (8 bf16) along n
  const int rr = t >> 3;             // d group (0..31)
#pragma unroll
  for (int i = 0; i < 2; ++i) {
    const int d = rr + 32 * i;
    unsigned int w[4];
#pragma unroll
    for (int j = 0; j < 4; ++j) {
      unsigned int a = tile[(ck * 8 + 2 * j)     * 66 + d];
      unsigned int b = tile[(ck * 8 + 2 * j + 1) * 66 + d];
      w[j] = a | (b << 16);
    }
    uint4 o; o.x = w[0]; o.y = w[1]; o.z = w[2]; o.w = w[3];
    *(uint4*)(xt + (size_t)(d0 + d) * K_DIM + n0 + ck * 8) = o;
  }
}

// ---------------- K2: init output to -0.5 ----------------------------------
__global__ __launch_bounds__(256) void init_out_kernel(float* __restrict__ out) {
  size_t i = (size_t)blockIdx.x * 256 + threadIdx.x;   // 147456 float4
  ((float4*)out)[i] = make_float4(-0.5f, -0.5f, -0.5f, -0.5f);
}

// ---------------- K3: Gram GEMM, symmetric upper tiles ---------------------
// grid (21, KSPLIT). pair p -> (mi, ni), mi <= ni.
__global__ __launch_bounds__(256, 4) void gram_gemm_kernel(
    const unsigned short* __restrict__ xt, float* __restrict__ out) {
  __shared__ __align__(16) unsigned short ldsA[128 * 32];  // 8 KiB
  __shared__ __align__(16) unsigned short ldsB[128 * 32];  // 8 KiB

  // decode triangular pair index
  int p = blockIdx.x, mi = 0, row = 6;
  while (p >= row) { p -= row; ++mi; --row; }
  const int ni = mi + p;
  const int m0 = mi * 128;
  const int n0 = ni * 128;
  const int kz = blockIdx.y;

  const int t    = threadIdx.x;
  const int wave = t >> 6;
  const int lane = t & 63;
  const int wm   = (wave >> 1) * 64;
  const int wn   = (wave & 1) * 64;
  const int lm   = lane & 15;
  const int quad = lane >> 4;

  floatx4 zero = {0.f, 0.f, 0.f, 0.f};
  floatx4 acc[4][4];
#pragma unroll
  for (int a = 0; a < 4; ++a)
#pragma unroll
    for (int b = 0; b < 4; ++b) acc[a][b] = zero;

  const int kbeg = kz * KCHUNK;

  for (int it = 0; it < KCHUNK / 32; ++it) {
    const int kb = kbeg + it * 32;
#pragma unroll
    for (int i = 0; i < 2; ++i) {
      const int c     = wave * 2 + i;
      const int flatL = c * 64 + lane;       // 0..511
      const int rrow  = flatL >> 2;          // tile row 0..127
      const int sub   = flatL & 3;           // 16B piece within row
      const unsigned short* gA = xt + (size_t)(m0 + rrow) * K_DIM + kb + sub * 8;
      const unsigned short* gB = xt + (size_t)(n0 + rrow) * K_DIM + kb + sub * 8;
      load_lds16(gA, &ldsA[flatL * 8]);
      load_lds16(gB, &ldsB[flatL * 8]);
    }
    __syncthreads();

    short8 af[4], bf[4];
#pragma unroll
    for (int a = 0; a < 4; ++a)
      af[a] = *(const short8*)&ldsA[(wm + a * 16 + lm) * 32 + quad * 8];
#pragma unroll
    for (int b = 0; b < 4; ++b)
      bf[b] = *(const short8*)&ldsB[(wn + b * 16 + lm) * 32 + quad * 8];

#pragma unroll
    for (int a = 0; a < 4; ++a)
#pragma unroll
      for (int b = 0; b < 4; ++b)
        acc[a][b] = __builtin_amdgcn_mfma_f32_16x16x32_bf16(
            af[a], bf[b], acc[a][b], 0, 0, 0);

    __syncthreads();
  }

  // epilogue: C/D layout col=lane&15, row=quad*4+reg (m89/m91-verified)
  const float scale = 0.5f / (float)K_DIM;
#pragma unroll
  for (int a = 0; a < 4; ++a)
#pragma unroll
    for (int b = 0; b < 4; ++b)
#pragma unroll
      for (int r2 = 0; r2 < 4; ++r2) {
        const int grow = m0 + wm + a * 16 + quad * 4 + r2;
        const int gcol = n0 + wn + b * 16 + lm;
        atomicAdd(&out[(size_t)grow * D_DIM + gcol], acc[a][b][r2] * scale);
      }
}

// ---------------- K4: mirror upper -> lower --------------------------------
__global__ __launch_bounds__(256) void mirror_kernel(float* __restrict__ out) {
  const int idx = blockIdx.x * 256 + threadIdx.x;      // 589824 total
  const int r = idx / D_DIM;
  const int c = idx - r * D_DIM;
  if ((r >> 7) > (c >> 7))                             // strictly-lower 128-tile
    out[idx] = out[(size_t)c * D_DIM + r];
}

extern "C" void kernel_launch(void* const* d_in, const int* in_sizes, int n_in,
                              void* d_out, int out_size, void* d_ws, size_t ws_size,
                              hipStream_t stream) {
  const float* x = (const float*)d_in[0];           // [16384,768] f32
  float* out = (float*)d_out;                       // [768,768] f32
  unsigned short* xt = (unsigned short*)d_ws;       // [768,16384] bf16 (24 MiB)

  transpose_cast_kernel<<<dim3(12, 256), 256, 0, stream>>>(x, xt);
  init_out_kernel<<<576, 256, 0, stream>>>(out);
  gram_gemm_kernel<<<dim3(21, KSPLIT), 256, 0, stream>>>(xt, out);
  mirror_kernel<<<2304, 256, 0, stream>>>(out);
}

// Round 3
// 116.117 us; speedup vs baseline: 1.2461x; 1.2461x over previous
//
#include <hip/hip_runtime.h>
#include <hip/hip_bf16.h>

// DecorrelationGradient, KAPPA = 0.5:
//   out = 0.5 * (X^T X / N) - 0.5   (diag terms cancel exactly at k=0.5)
// X [16384, 768] fp32.
//
// R3: atomic epilogue was the wall (56us invariant under -42% MFMA work;
//     WRITE_SIZE == atomic bytes -> memory-side RMW writethrough).
// K1: transpose+cast X -> XT [768,16384] bf16 in d_ws
// K3: MFMA GEMM, upper tile-pairs only, 128x128, BK=32, KSPLIT=32,
//     partials stored as bf16 to d_ws (NO atomics)
// K4: reduce 32 partials -> affine -> write tile + mirrored transpose
//     (subsumes init and mirror kernels)

#define D_DIM    768
#define K_DIM    16384
#define NPAIR    21
#define KSPLIT   32
#define KCHUNK   (K_DIM / KSPLIT)       // 512 -> 16 iters of BK=32
#define XT_BYTES ((size_t)D_DIM * K_DIM * 2)                  // 24 MiB
#define PART_BYTES ((size_t)KSPLIT * NPAIR * 16384 * 2)       // 21 MiB

__device__ __constant__ int MI_TAB[NPAIR] = {0,0,0,0,0,0, 1,1,1,1,1, 2,2,2,2, 3,3,3, 4,4, 5};
__device__ __constant__ int NI_TAB[NPAIR] = {0,1,2,3,4,5, 1,2,3,4,5, 2,3,4,5, 3,4,5, 4,5, 5};

typedef __attribute__((ext_vector_type(8))) short short8;     // bf16 A/B frag
typedef __attribute__((ext_vector_type(4))) float floatx4;    // fp32 C/D frag

typedef __attribute__((address_space(3))) unsigned short lds_ushort;
typedef __attribute__((address_space(1))) const unsigned short g_ushort;

__device__ __forceinline__ void load_lds16(const unsigned short* g, unsigned short* l) {
  __builtin_amdgcn_global_load_lds((g_ushort*)g, (lds_ushort*)l, 16, 0, 0);
}

__device__ __forceinline__ unsigned short f2bf(float f) {
  unsigned int u = __float_as_uint(f);
  u += 0x7fffu + ((u >> 16) & 1u);
  return (unsigned short)(u >> 16);
}
__device__ __forceinline__ float bf2f(unsigned short u) {
  return __uint_as_float((unsigned int)u << 16);
}

// ---------------- K1: transpose + cast -------------------------------------
__global__ __launch_bounds__(256) void transpose_cast_kernel(
    const float* __restrict__ x, unsigned short* __restrict__ xt) {
  __shared__ __align__(16) unsigned short tile[64 * 66];
  const int d0 = blockIdx.x * 64;
  const int n0 = blockIdx.y * 64;
  const int t  = threadIdx.x;
  const int c4 = t & 15;
  const int r  = t >> 4;
#pragma unroll
  for (int i = 0; i < 4; ++i) {
    const int n = r + 16 * i;
    float4 v = *(const float4*)(x + (size_t)(n0 + n) * D_DIM + d0 + c4 * 4);
    ushort2 lo, hi;
    lo.x = f2bf(v.x); lo.y = f2bf(v.y);
    hi.x = f2bf(v.z); hi.y = f2bf(v.w);
    *(ushort2*)&tile[n * 66 + c4 * 4]     = lo;
    *(ushort2*)&tile[n * 66 + c4 * 4 + 2] = hi;
  }
  __syncthreads();
  const int ck = t & 7;
  const int rr = t >> 3;
#pragma unroll
  for (int i = 0; i < 2; ++i) {
    const int d = rr + 32 * i;
    unsigned int w[4];
#pragma unroll
    for (int j = 0; j < 4; ++j) {
      unsigned int a = tile[(ck * 8 + 2 * j)     * 66 + d];
      unsigned int b = tile[(ck * 8 + 2 * j + 1) * 66 + d];
      w[j] = a | (b << 16);
    }
    uint4 o; o.x = w[0]; o.y = w[1]; o.z = w[2]; o.w = w[3];
    *(uint4*)(xt + (size_t)(d0 + d) * K_DIM + n0 + ck * 8) = o;
  }
}

// ---------------- K3: Gram GEMM, partials or atomic fallback ---------------
template<int KS, bool ATOMIC>
__global__ __launch_bounds__(256, 4) void gram_gemm_kernel(
    const unsigned short* __restrict__ xt,
    unsigned short* __restrict__ partials,   // bf16 [KS][NPAIR][16384]
    float* __restrict__ out) {
  __shared__ __align__(16) unsigned short ldsA[128 * 32];
  __shared__ __align__(16) unsigned short ldsB[128 * 32];

  const int p  = blockIdx.x;
  const int mi = MI_TAB[p];
  const int ni = NI_TAB[p];
  const int m0 = mi * 128;
  const int n0 = ni * 128;
  const int kz = blockIdx.y;

  const int t    = threadIdx.x;
  const int wave = t >> 6;
  const int lane = t & 63;
  const int wm   = (wave >> 1) * 64;
  const int wn   = (wave & 1) * 64;
  const int lm   = lane & 15;
  const int quad = lane >> 4;

  floatx4 zero = {0.f, 0.f, 0.f, 0.f};
  floatx4 acc[4][4];
#pragma unroll
  for (int a = 0; a < 4; ++a)
#pragma unroll
    for (int b = 0; b < 4; ++b) acc[a][b] = zero;

  const int kbeg = kz * (K_DIM / KS);

  for (int it = 0; it < (K_DIM / KS) / 32; ++it) {
    const int kb = kbeg + it * 32;
#pragma unroll
    for (int i = 0; i < 2; ++i) {
      const int c     = wave * 2 + i;
      const int flatL = c * 64 + lane;
      const int rrow  = flatL >> 2;
      const int sub   = flatL & 3;
      const unsigned short* gA = xt + (size_t)(m0 + rrow) * K_DIM + kb + sub * 8;
      const unsigned short* gB = xt + (size_t)(n0 + rrow) * K_DIM + kb + sub * 8;
      load_lds16(gA, &ldsA[flatL * 8]);
      load_lds16(gB, &ldsB[flatL * 8]);
    }
    __syncthreads();

    short8 af[4], bf[4];
#pragma unroll
    for (int a = 0; a < 4; ++a)
      af[a] = *(const short8*)&ldsA[(wm + a * 16 + lm) * 32 + quad * 8];
#pragma unroll
    for (int b = 0; b < 4; ++b)
      bf[b] = *(const short8*)&ldsB[(wn + b * 16 + lm) * 32 + quad * 8];

#pragma unroll
    for (int a = 0; a < 4; ++a)
#pragma unroll
      for (int b = 0; b < 4; ++b)
        acc[a][b] = __builtin_amdgcn_mfma_f32_16x16x32_bf16(
            af[a], bf[b], acc[a][b], 0, 0, 0);

    __syncthreads();
  }

  if (ATOMIC) {
    const float scale = 0.5f / (float)K_DIM;
#pragma unroll
    for (int a = 0; a < 4; ++a)
#pragma unroll
      for (int b = 0; b < 4; ++b)
#pragma unroll
        for (int r2 = 0; r2 < 4; ++r2) {
          const int grow = m0 + wm + a * 16 + quad * 4 + r2;
          const int gcol = n0 + wn + b * 16 + lm;
          atomicAdd(&out[(size_t)grow * D_DIM + gcol], acc[a][b][r2] * scale);
        }
  } else {
    // store raw bf16 partial, local row-major 128x128
    unsigned short* pb = partials + ((size_t)kz * NPAIR + p) * 16384;
#pragma unroll
    for (int a = 0; a < 4; ++a)
#pragma unroll
      for (int b = 0; b < 4; ++b)
#pragma unroll
        for (int r2 = 0; r2 < 4; ++r2) {
          const int lr = wm + a * 16 + quad * 4 + r2;
          const int lc = wn + b * 16 + lm;
          pb[lr * 128 + lc] = f2bf(acc[a][b][r2]);
        }
  }
}

// ---------------- K4: reduce + affine + mirror -----------------------------
// grid: 21*16384/256 = 1344 blocks. Thread g -> (pair t, elem e).
__global__ __launch_bounds__(256) void reduce_kernel(
    const unsigned short* __restrict__ partials, float* __restrict__ out) {
  const int g = blockIdx.x * 256 + threadIdx.x;
  const int t = g >> 14;            // wave-uniform (16384 elems per tile)
  const int e = g & 16383;
  float s = 0.f;
#pragma unroll
  for (int kz = 0; kz < KSPLIT; ++kz)
    s += bf2f(partials[((size_t)kz * NPAIR + t) * 16384 + e]);
  const float v = s * (0.5f / (float)K_DIM) - 0.5f;
  const int mi = MI_TAB[t], ni = NI_TAB[t];
  const int r = e >> 7, c = e & 127;
  const int gr = mi * 128 + r, gc = ni * 128 + c;
  out[(size_t)gr * D_DIM + gc] = v;
  if (mi != ni) out[(size_t)gc * D_DIM + gr] = v;   // symmetric mirror
}

// ---------------- fallback init (atomic path only) -------------------------
__global__ __launch_bounds__(256) void init_out_kernel(float* __restrict__ out) {
  size_t i = (size_t)blockIdx.x * 256 + threadIdx.x;
  ((float4*)out)[i] = make_float4(-0.5f, -0.5f, -0.5f, -0.5f);
}
__global__ __launch_bounds__(256) void mirror_kernel(float* __restrict__ out) {
  const int idx = blockIdx.x * 256 + threadIdx.x;
  const int r = idx / D_DIM;
  const int c = idx - r * D_DIM;
  if ((r >> 7) > (c >> 7))
    out[idx] = out[(size_t)c * D_DIM + r];
}

extern "C" void kernel_launch(void* const* d_in, const int* in_sizes, int n_in,
                              void* d_out, int out_size, void* d_ws, size_t ws_size,
                              hipStream_t stream) {
  const float* x = (const float*)d_in[0];           // [16384,768] f32
  float* out = (float*)d_out;                       // [768,768] f32
  unsigned short* xt = (unsigned short*)d_ws;       // bf16 [768][16384]

  transpose_cast_kernel<<<dim3(12, 256), 256, 0, stream>>>(x, xt);

  if (ws_size >= XT_BYTES + PART_BYTES) {
    unsigned short* parts = (unsigned short*)((char*)d_ws + XT_BYTES);
    gram_gemm_kernel<KSPLIT, false><<<dim3(NPAIR, KSPLIT), 256, 0, stream>>>(xt, parts, out);
    reduce_kernel<<<NPAIR * 16384 / 256, 256, 0, stream>>>(parts, out);
  } else {
    // atomic fallback (slower, small ws): KSPLIT=8 to limit RMW contention
    init_out_kernel<<<576, 256, 0, stream>>>(out);
    gram_gemm_kernel<8, true><<<dim3(NPAIR, 8), 256, 0, stream>>>(xt, nullptr, out);
    mirror_kernel<<<2304, 256, 0, stream>>>(out);
  }
}